// Round 4
// baseline (626.890 us; speedup 1.0000x reference)
//
#include <hip/hip_runtime.h>
#include <hip/hip_bf16.h>

// ---------------------------------------------------------------------------
// ASGNN round 4: binned CSR build (kills fill_k's 105 MB write amplification).
//  K0 cvt_x       : xb = bf16(x)
//  K1 prep_w      : Wb[j][k] = bf16 of stacked [W1l | W1r] rows (j-major)
//  K2 degree_k    : deg[dst]++
//  K3 scan_blk/top/add : row_ptr = exscan(deg)
//  K4 init_bcur   : bcur[b] = row_ptr[b*128]
//  K5 bin_k       : ebuf[bcur[dst>>7]++] = (src,dst)   (bucket-contiguous)
//  K6 fill2_k     : per-bucket WG, LDS cursors: csr[lcur[dst]++] = src
//  K7 gather_mean : aggb[n] = bf16(mean_{s in nbr(n)} xb[s])
//  K8 gemm_mfma   : h = relu([aggb|xb] @ Wb^T + b1l); t=W2l.h, r=W2r.h fused
//  K9 final_k     : z = mean_s t[s] + b2l + r ; out = mu + eps*exp(logvar)
// ---------------------------------------------------------------------------

#define F_DIM 128
#define NFEAT2 256
#define BUK_BITS 7
#define BUK_SZ 128

typedef __bf16 b8 __attribute__((ext_vector_type(8)));
typedef float  f4 __attribute__((ext_vector_type(4)));

__device__ inline float bf2f(unsigned short u) {
    unsigned int v = ((unsigned int)u) << 16;
    return __uint_as_float(v);
}
__device__ inline unsigned short f2bf(float f) {
    unsigned int u = __float_as_uint(f);
    u += 0x7fffu + ((u >> 16) & 1u);
    return (unsigned short)(u >> 16);
}

__global__ void cvt_x(const float* __restrict__ x, unsigned short* __restrict__ xb, int n4) {
    int i = blockIdx.x * blockDim.x + threadIdx.x;
    if (i >= n4) return;
    float4 v = *(const float4*)(x + (size_t)i * 4);
    ushort4 o;
    o.x = f2bf(v.x); o.y = f2bf(v.y); o.z = f2bf(v.z); o.w = f2bf(v.w);
    *(ushort4*)(xb + (size_t)i * 4) = o;
}

__global__ void prep_w(const float* __restrict__ W1l, const float* __restrict__ W1r,
                       unsigned short* __restrict__ Wb) {
    int idx = blockIdx.x * blockDim.x + threadIdx.x;   // 65536
    int j = idx >> 8;
    int k = idx & 255;
    float v = (k < F_DIM) ? W1l[j * F_DIM + k] : W1r[j * F_DIM + (k - F_DIM)];
    Wb[j * NFEAT2 + k] = f2bf(v);
}

__global__ void degree_k(const int* __restrict__ dst, int* __restrict__ deg, int E) {
    int e = blockIdx.x * blockDim.x + threadIdx.x;
    if (e >= E) return;
    atomicAdd(&deg[dst[e]], 1);
}

__global__ __launch_bounds__(1024)
void scan_blk(const int* __restrict__ deg, int* __restrict__ row_ptr,
              int* __restrict__ bsum, int Nn) {
    __shared__ int wsum[16];
    int tid = threadIdx.x, lane = tid & 63, w = tid >> 6;
    int i = blockIdx.x * 1024 + tid;
    int v = (i < Nn) ? deg[i] : 0;
    int sc = v;
    #pragma unroll
    for (int off = 1; off < 64; off <<= 1) {
        int t = __shfl_up(sc, off, 64);
        if (lane >= off) sc += t;
    }
    if (lane == 63) wsum[w] = sc;
    __syncthreads();
    int woff = 0;
    for (int k = 0; k < w; ++k) woff += wsum[k];
    if (i < Nn) row_ptr[i] = sc - v + woff;     // block-local exclusive
    if (tid == 1023) bsum[blockIdx.x] = woff + sc;
}

__global__ __launch_bounds__(128)
void scan_top(const int* __restrict__ bsum, int* __restrict__ boff,
              int* __restrict__ row_ptr, int nb, int Nn) {
    __shared__ int ws2[2];
    int tid = threadIdx.x, lane = tid & 63, w = tid >> 6;
    int v = (tid < nb) ? bsum[tid] : 0;
    int sc = v;
    #pragma unroll
    for (int off = 1; off < 64; off <<= 1) {
        int t = __shfl_up(sc, off, 64);
        if (lane >= off) sc += t;
    }
    if (lane == 63) ws2[w] = sc;
    __syncthreads();
    int woff = (w == 1) ? ws2[0] : 0;
    if (tid < nb) boff[tid] = sc - v + woff;
    __syncthreads();
    if (tid == 0) row_ptr[Nn] = ws2[0] + ws2[1];
}

__global__ void scan_add(int* __restrict__ row_ptr, const int* __restrict__ boff, int Nn) {
    int i = blockIdx.x * blockDim.x + threadIdx.x;
    if (i >= Nn) return;
    row_ptr[i] += boff[i >> 10];
}

__global__ void init_bcur(const int* __restrict__ row_ptr, int* __restrict__ bcur, int nbuk) {
    int b = blockIdx.x * blockDim.x + threadIdx.x;
    if (b >= nbuk) return;
    bcur[b] = row_ptr[b << BUK_BITS];
}

__global__ void bin_k(const int* __restrict__ src, const int* __restrict__ dst,
                      int* __restrict__ bcur, uint2* __restrict__ ebuf, int E) {
    int e = blockIdx.x * blockDim.x + threadIdx.x;
    if (e >= E) return;
    int s = src[e], d = dst[e];
    int p = atomicAdd(&bcur[d >> BUK_BITS], 1);
    ebuf[p] = make_uint2((unsigned)s, (unsigned)d);
}

__global__ __launch_bounds__(256)
void fill2_k(const uint2* __restrict__ ebuf, const int* __restrict__ row_ptr,
             int* __restrict__ csr, int Nn) {
    __shared__ int lcur[BUK_SZ];
    int node0 = blockIdx.x << BUK_BITS;
    int nn = min(BUK_SZ, Nn - node0);
    int tid = threadIdx.x;
    if (tid < nn) lcur[tid] = row_ptr[node0 + tid];
    __syncthreads();
    int beg = row_ptr[node0];
    int end = row_ptr[node0 + nn];
    for (int i = beg + tid; i < end; i += 256) {
        uint2 e = ebuf[i];
        int p = atomicAdd(&lcur[(int)e.y - node0], 1);
        csr[p] = (int)e.x;
    }
}

// 16 nodes per 256-thread block; 16 lanes/node, 16B (8 bf16) per lane
__global__ __launch_bounds__(256)
void gather_mean(const unsigned short* __restrict__ xb, const int* __restrict__ row_ptr,
                 const int* __restrict__ csr, unsigned short* __restrict__ aggb, int Nn) {
    int node = blockIdx.x * 16 + (threadIdx.x >> 4);
    int q = threadIdx.x & 15;
    if (node >= Nn) return;
    int beg = row_ptr[node], end = row_ptr[node + 1];
    float a[8] = {};
    int j = beg;
    for (; j + 1 < end; j += 2) {
        int s0 = csr[j], s1 = csr[j + 1];
        uint4 r0 = *(const uint4*)(xb + (size_t)s0 * F_DIM + q * 8);
        uint4 r1 = *(const uint4*)(xb + (size_t)s1 * F_DIM + q * 8);
        a[0] += bf2f(r0.x & 0xffff) + bf2f(r1.x & 0xffff);
        a[1] += bf2f(r0.x >> 16)    + bf2f(r1.x >> 16);
        a[2] += bf2f(r0.y & 0xffff) + bf2f(r1.y & 0xffff);
        a[3] += bf2f(r0.y >> 16)    + bf2f(r1.y >> 16);
        a[4] += bf2f(r0.z & 0xffff) + bf2f(r1.z & 0xffff);
        a[5] += bf2f(r0.z >> 16)    + bf2f(r1.z >> 16);
        a[6] += bf2f(r0.w & 0xffff) + bf2f(r1.w & 0xffff);
        a[7] += bf2f(r0.w >> 16)    + bf2f(r1.w >> 16);
    }
    if (j < end) {
        int s0 = csr[j];
        uint4 r0 = *(const uint4*)(xb + (size_t)s0 * F_DIM + q * 8);
        a[0] += bf2f(r0.x & 0xffff);
        a[1] += bf2f(r0.x >> 16);
        a[2] += bf2f(r0.y & 0xffff);
        a[3] += bf2f(r0.y >> 16);
        a[4] += bf2f(r0.z & 0xffff);
        a[5] += bf2f(r0.z >> 16);
        a[6] += bf2f(r0.w & 0xffff);
        a[7] += bf2f(r0.w >> 16);
    }
    float inv = 1.0f / fmaxf((float)(end - beg), 1.0f);
    uint4 o;
    o.x = (unsigned)f2bf(a[0] * inv) | ((unsigned)f2bf(a[1] * inv) << 16);
    o.y = (unsigned)f2bf(a[2] * inv) | ((unsigned)f2bf(a[3] * inv) << 16);
    o.z = (unsigned)f2bf(a[4] * inv) | ((unsigned)f2bf(a[5] * inv) << 16);
    o.w = (unsigned)f2bf(a[6] * inv) | ((unsigned)f2bf(a[7] * inv) << 16);
    *(uint4*)(aggb + (size_t)node * F_DIM + q * 8) = o;
}

// 128x128 tile, K=256 in 4 steps of 64. 4 waves (2x2), each 64x64 output.
__global__ __launch_bounds__(256)
void gemm_mfma(const unsigned short* __restrict__ aggb, const unsigned short* __restrict__ xb,
               const unsigned short* __restrict__ Wb, const float* __restrict__ b1l,
               const float* __restrict__ W2l, const float* __restrict__ W2r,
               float* __restrict__ tv, float* __restrict__ rv, int Nn) {
    __shared__ unsigned short Al[128 * 64];   // 16 KB
    __shared__ unsigned short Bl[128 * 64];   // 16 KB
    int mb = blockIdx.x >> 1;
    int jb = blockIdx.x & 1;
    int m0 = mb * 128;
    int tid = threadIdx.x;
    int lane = tid & 63, wid = tid >> 6;
    int wm = wid >> 1, wj = wid & 1;

    f4 acc[4][4] = {};

    for (int kstep = 0; kstep < 4; ++kstep) {
        const unsigned short* Asrc = (kstep < 2) ? aggb : xb;
        int kbase = (kstep & 1) * 64;
        #pragma unroll
        for (int pass = 0; pass < 4; ++pass) {
            int c = tid + pass * 256;
            int m = c >> 3, kc = c & 7;
            int gn = m0 + m;
            uint4 v = make_uint4(0u, 0u, 0u, 0u);
            if (gn < Nn) v = *(const uint4*)(Asrc + (size_t)gn * F_DIM + kbase + kc * 8);
            int byte = (m * 128 + kc * 16) ^ ((m & 7) << 4);
            *(uint4*)((char*)Al + byte) = v;
        }
        #pragma unroll
        for (int pass = 0; pass < 4; ++pass) {
            int c = tid + pass * 256;
            int jj = c >> 3, kc = c & 7;
            uint4 v = *(const uint4*)(Wb + (size_t)(jb * 128 + jj) * NFEAT2 + kstep * 64 + kc * 8);
            int byte = (jj * 128 + kc * 16) ^ ((jj & 7) << 4);
            *(uint4*)((char*)Bl + byte) = v;
        }
        __syncthreads();

        #pragma unroll
        for (int ks = 0; ks < 2; ++ks) {
            int kk2 = (ks * 32 + ((lane >> 4) << 3)) * 2;   // byte offset in row
            b8 af[4], bfr[4];
            #pragma unroll
            for (int fm = 0; fm < 4; ++fm) {
                int m = (wm << 6) + (fm << 4) + (lane & 15);
                int byte = (m * 128 + kk2) ^ ((m & 7) << 4);
                af[fm] = *(const b8*)((const char*)Al + byte);
            }
            #pragma unroll
            for (int fj = 0; fj < 4; ++fj) {
                int jj = (wj << 6) + (fj << 4) + (lane & 15);
                int byte = (jj * 128 + kk2) ^ ((jj & 7) << 4);
                bfr[fj] = *(const b8*)((const char*)Bl + byte);
            }
            #pragma unroll
            for (int fm = 0; fm < 4; ++fm)
                #pragma unroll
                for (int fj = 0; fj < 4; ++fj)
                    acc[fm][fj] = __builtin_amdgcn_mfma_f32_16x16x32_bf16(
                        af[fm], bfr[fj], acc[fm][fj], 0, 0, 0);
        }
        __syncthreads();
    }

    float bb[4], wl[4], wr[4];
    #pragma unroll
    for (int fj = 0; fj < 4; ++fj) {
        int j_abs = jb * 128 + (wj << 6) + (fj << 4) + (lane & 15);
        bb[fj] = b1l[j_abs];
        wl[fj] = W2l[j_abs];
        wr[fj] = W2r[j_abs];
    }
    #pragma unroll
    for (int fm = 0; fm < 4; ++fm) {
        #pragma unroll
        for (int reg = 0; reg < 4; ++reg) {
            int row = m0 + (wm << 6) + (fm << 4) + ((lane >> 4) << 2) + reg;
            float tp = 0.f, rp = 0.f;
            #pragma unroll
            for (int fj = 0; fj < 4; ++fj) {
                float h = fmaxf(acc[fm][fj][reg] + bb[fj], 0.0f);
                tp += wl[fj] * h;
                rp += wr[fj] * h;
            }
            #pragma unroll
            for (int mask = 1; mask < 16; mask <<= 1) {
                tp += __shfl_xor(tp, mask, 64);
                rp += __shfl_xor(rp, mask, 64);
            }
            if ((lane & 15) == 0 && row < Nn) {
                atomicAdd(&tv[row], tp);
                atomicAdd(&rv[row], rp);
            }
        }
    }
}

__global__ void final_k(const float* __restrict__ t, const int* __restrict__ row_ptr,
                        const int* __restrict__ csr, const float* __restrict__ r,
                        const float* __restrict__ b2l,
                        const float* __restrict__ Wmu, const float* __restrict__ bmu,
                        const float* __restrict__ Wlv, const float* __restrict__ blv,
                        const float* __restrict__ eps, float* __restrict__ out, int Nn) {
    int i = blockIdx.x * blockDim.x + threadIdx.x;
    if (i >= Nn) return;
    int beg = row_ptr[i], end = row_ptr[i + 1];
    float s = 0.f;
    for (int j = beg; j < end; ++j) s += t[csr[j]];
    float z = s / fmaxf((float)(end - beg), 1.0f) + b2l[0] + r[i];
    float mu = z * Wmu[0] + bmu[0];
    float lv = z * Wlv[0] + blv[0];
    out[i] = mu + eps[i] * expf(lv);
}

extern "C" void kernel_launch(void* const* d_in, const int* in_sizes, int n_in,
                              void* d_out, int out_size, void* d_ws, size_t ws_size,
                              hipStream_t stream) {
    const float* x   = (const float*)d_in[0];
    const int*   ei  = (const int*)d_in[1];
    const float* W1l = (const float*)d_in[2];
    const float* b1l = (const float*)d_in[3];
    const float* W1r = (const float*)d_in[4];
    const float* W2l = (const float*)d_in[5];
    const float* b2l = (const float*)d_in[6];
    const float* W2r = (const float*)d_in[7];
    // d_in[8..10] = Wal, bal, War : dead (softmax over size-1 axis == 1)
    const float* Wmu = (const float*)d_in[11];
    const float* bmu = (const float*)d_in[12];
    const float* Wlv = (const float*)d_in[13];
    const float* blv = (const float*)d_in[14];
    const float* eps = (const float*)d_in[15];
    float* out = (float*)d_out;

    const int Nn = in_sizes[0] / F_DIM;   // 100000
    const int E  = in_sizes[1] / 2;       // 1600000
    const int* src = ei;
    const int* dst = ei + E;
    const int nbuk = (Nn + BUK_SZ - 1) >> BUK_BITS;

    char* ws = (char*)d_ws;
    int*            deg     = (int*)(ws + 0);              // N
    float*          tv      = (float*)(ws + 400000);       // N
    float*          rv      = (float*)(ws + 800000);       // N
    int*            row_ptr = (int*)(ws + 1200000);        // N+1
    int*            bsum    = (int*)(ws + 1600016);        // <=1024
    int*            boff    = (int*)(ws + 1604112);        // <=1024
    int*            bcur    = (int*)(ws + 1608208);        // nbuk (<=1024)
    int*            csr     = (int*)(ws + 1612304);        // E ints
    unsigned short* xb      = (unsigned short*)(ws + 8012304);   // N*128 bf16
    unsigned short* aggb    = (unsigned short*)(ws + 33612304);  // N*128 bf16
    uint2*          ebuf    = (uint2*)(ws + 33612304);           // E*8B (aliases aggb)
    unsigned short* Wb      = (unsigned short*)(ws + 59212304);  // 256*256 bf16

    hipMemsetAsync(ws, 0, 1200000, stream);   // deg, tv, rv

    cvt_x<<<(Nn * F_DIM / 4 + 255) / 256, 256, 0, stream>>>(x, xb, Nn * F_DIM / 4);
    prep_w<<<256, 256, 0, stream>>>(W1l, W1r, Wb);

    degree_k<<<(E + 255) / 256, 256, 0, stream>>>(dst, deg, E);
    int nb = (Nn + 1023) / 1024;
    scan_blk<<<nb, 1024, 0, stream>>>(deg, row_ptr, bsum, Nn);
    scan_top<<<1, 128, 0, stream>>>(bsum, boff, row_ptr, nb, Nn);
    scan_add<<<(Nn + 255) / 256, 256, 0, stream>>>(row_ptr, boff, Nn);
    init_bcur<<<(nbuk + 255) / 256, 256, 0, stream>>>(row_ptr, bcur, nbuk);
    bin_k<<<(E + 255) / 256, 256, 0, stream>>>(src, dst, bcur, ebuf, E);
    fill2_k<<<nbuk, 256, 0, stream>>>(ebuf, row_ptr, csr, Nn);

    gather_mean<<<(Nn + 15) / 16, 256, 0, stream>>>(xb, row_ptr, csr, aggb, Nn);

    {
        int mblocks = (Nn + 127) / 128;
        gemm_mfma<<<mblocks * 2, 256, 0, stream>>>(aggb, xb, Wb, b1l, W2l, W2r,
                                                   tv, rv, Nn);
    }

    final_k<<<(Nn + 255) / 256, 256, 0, stream>>>(tv, row_ptr, csr, rv, b2l,
                                                  Wmu, bmu, Wlv, blv, eps, out, Nn);
}

// Round 5
// 204.508 us; speedup vs baseline: 3.0654x; 3.0654x over previous
//
#include <hip/hip_runtime.h>
#include <hip/hip_bf16.h>

// ---------------------------------------------------------------------------
// ASGNN round 5: privatized counting-sort CSR build.
//  - bin_k's 782-counter global atomics (2046 ops/addr, 377us) -> LDS-private
//    histograms + segmented placement. Also folds degree+scan into fill3_k.
//  K0 cvt_x      : xb = bf16(x)
//  K1 prep_w     : Wb[j][k] = bf16 of stacked [W1l | W1r] rows (j-major)
//  K2 hist_k     : hist[g][b] = #edges of chunk g with dst in bucket b
//  K3 colsum/exscan/colscan : gbase[b][g] = bucket_base[b] + prefix_g
//  K4 scatter2_k : ebuf[gbase cursor] = (src,dst)  (LDS cursors, dense segs)
//  K5 fill3_k    : per-bucket node counts -> row_ptr ; csr[lcur[dst]++] = src
//  K6 gather_mean: aggb[n] = bf16(mean_{s in nbr(n)} xb[s])
//  K7 gemm_mfma  : h = relu([aggb|xb] @ Wb^T + b1l); t=W2l.h, r=W2r.h fused
//  K8 final_k    : z = mean_s t[s] + b2l + r ; out = mu + eps*exp(logvar)
// ---------------------------------------------------------------------------

#define F_DIM 128
#define NFEAT2 256
#define BUK_BITS 7
#define BUK_SZ 128
#define GROUPS 128

typedef __bf16 b8 __attribute__((ext_vector_type(8)));
typedef float  f4 __attribute__((ext_vector_type(4)));

__device__ inline float bf2f(unsigned short u) {
    unsigned int v = ((unsigned int)u) << 16;
    return __uint_as_float(v);
}
__device__ inline unsigned short f2bf(float f) {
    unsigned int u = __float_as_uint(f);
    u += 0x7fffu + ((u >> 16) & 1u);
    return (unsigned short)(u >> 16);
}

__global__ void cvt_x(const float* __restrict__ x, unsigned short* __restrict__ xb, int n4) {
    int i = blockIdx.x * blockDim.x + threadIdx.x;
    if (i >= n4) return;
    float4 v = *(const float4*)(x + (size_t)i * 4);
    ushort4 o;
    o.x = f2bf(v.x); o.y = f2bf(v.y); o.z = f2bf(v.z); o.w = f2bf(v.w);
    *(ushort4*)(xb + (size_t)i * 4) = o;
}

__global__ void prep_w(const float* __restrict__ W1l, const float* __restrict__ W1r,
                       unsigned short* __restrict__ Wb) {
    int idx = blockIdx.x * blockDim.x + threadIdx.x;   // 65536
    int j = idx >> 8;
    int k = idx & 255;
    float v = (k < F_DIM) ? W1l[j * F_DIM + k] : W1r[j * F_DIM + (k - F_DIM)];
    Wb[j * NFEAT2 + k] = f2bf(v);
}

// per-group LDS histogram of dst buckets
__global__ __launch_bounds__(256)
void hist_k(const int* __restrict__ dst, int* __restrict__ hist,
            int E, int nbuk, int chunk) {
    __shared__ int h[1024];
    int g = blockIdx.x, tid = threadIdx.x;
    for (int i = tid; i < nbuk; i += 256) h[i] = 0;
    __syncthreads();
    int e0 = g * chunk, e1 = min(e0 + chunk, E);
    for (int e = e0 + tid; e < e1; e += 256)
        atomicAdd(&h[dst[e] >> BUK_BITS], 1);
    __syncthreads();
    for (int i = tid; i < nbuk; i += 256) hist[g * nbuk + i] = h[i];
}

__global__ void colsum_k(const int* __restrict__ hist, int* __restrict__ T, int nbuk) {
    int b = blockIdx.x * blockDim.x + threadIdx.x;
    if (b >= nbuk) return;
    int s = 0;
    for (int g = 0; g < GROUPS; ++g) s += hist[g * nbuk + b];
    T[b] = s;
}

// single-block exclusive scan over nbuk (<=1024) bucket totals
__global__ __launch_bounds__(1024)
void exscan_k(const int* __restrict__ T, int* __restrict__ bbase, int nbuk) {
    __shared__ int wsum[16];
    int tid = threadIdx.x, lane = tid & 63, w = tid >> 6;
    int v = (tid < nbuk) ? T[tid] : 0;
    int sc = v;
    #pragma unroll
    for (int off = 1; off < 64; off <<= 1) {
        int t = __shfl_up(sc, off, 64);
        if (lane >= off) sc += t;
    }
    if (lane == 63) wsum[w] = sc;
    __syncthreads();
    int woff = 0;
    for (int k = 0; k < w; ++k) woff += wsum[k];
    if (tid < nbuk) bbase[tid] = sc - v + woff;
    if (tid == 1023) bbase[nbuk] = woff + sc;
}

// per-bucket column scan over groups: gbase[b*G+g] = bbase[b] + prefix_g
__global__ __launch_bounds__(GROUPS)
void colscan_k(const int* __restrict__ hist, const int* __restrict__ bbase,
               int* __restrict__ gbase, int nbuk) {
    __shared__ int ws2[2];
    int b = blockIdx.x, tid = threadIdx.x;
    int lane = tid & 63, w = tid >> 6;
    int v = hist[tid * nbuk + b];
    int sc = v;
    #pragma unroll
    for (int off = 1; off < 64; off <<= 1) {
        int t = __shfl_up(sc, off, 64);
        if (lane >= off) sc += t;
    }
    if (lane == 63) ws2[w] = sc;
    __syncthreads();
    int excl = sc - v + (w ? ws2[0] : 0);
    gbase[b * GROUPS + tid] = bbase[b] + excl;
}

// re-read chunk, place (src,dst) via LDS cursors into per-(g,b) segments
__global__ __launch_bounds__(256)
void scatter2_k(const int* __restrict__ src, const int* __restrict__ dst,
                const int* __restrict__ gbase, uint2* __restrict__ ebuf,
                int E, int nbuk, int chunk) {
    __shared__ int lcur[1024];
    int g = blockIdx.x, tid = threadIdx.x;
    for (int i = tid; i < nbuk; i += 256) lcur[i] = gbase[i * GROUPS + g];
    __syncthreads();
    int e0 = g * chunk, e1 = min(e0 + chunk, E);
    for (int e = e0 + tid; e < e1; e += 256) {
        int s = src[e], d = dst[e];
        int p = atomicAdd(&lcur[d >> BUK_BITS], 1);
        ebuf[p] = make_uint2((unsigned)s, (unsigned)d);
    }
}

// per-bucket: node counts -> row_ptr (in-WG scan) -> place csr
__global__ __launch_bounds__(256)
void fill3_k(const uint2* __restrict__ ebuf, const int* __restrict__ bbase,
             int* __restrict__ row_ptr, int* __restrict__ csr, int Nn, int nbuk) {
    __shared__ int ncnt[BUK_SZ];
    __shared__ int lcur[BUK_SZ];
    __shared__ int ws2[2];
    int b = blockIdx.x, tid = threadIdx.x;
    int node0 = b << BUK_BITS;
    int base = bbase[b], endp = bbase[b + 1];
    if (tid < BUK_SZ) ncnt[tid] = 0;
    __syncthreads();
    for (int i = base + tid; i < endp; i += 256)
        atomicAdd(&ncnt[(int)ebuf[i].y & (BUK_SZ - 1)], 1);
    __syncthreads();
    int v = 0, sc = 0;
    int lane = tid & 63, w = tid >> 6;
    if (tid < BUK_SZ) {
        v = ncnt[tid];
        sc = v;
        #pragma unroll
        for (int off = 1; off < 64; off <<= 1) {
            int t = __shfl_up(sc, off, 64);
            if (lane >= off) sc += t;
        }
        if (lane == 63) ws2[w] = sc;
    }
    __syncthreads();
    if (tid < BUK_SZ) {
        int pos = base + sc - v + (w ? ws2[0] : 0);
        lcur[tid] = pos;
        if (node0 + tid < Nn) row_ptr[node0 + tid] = pos;
    }
    if (b == nbuk - 1 && tid == 0) row_ptr[Nn] = endp;
    __syncthreads();
    for (int i = base + tid; i < endp; i += 256) {
        uint2 e = ebuf[i];
        int p = atomicAdd(&lcur[(int)e.y & (BUK_SZ - 1)], 1);
        csr[p] = (int)e.x;
    }
}

// 16 nodes per 256-thread block; 16 lanes/node, 16B (8 bf16) per lane
__global__ __launch_bounds__(256)
void gather_mean(const unsigned short* __restrict__ xb, const int* __restrict__ row_ptr,
                 const int* __restrict__ csr, unsigned short* __restrict__ aggb, int Nn) {
    int node = blockIdx.x * 16 + (threadIdx.x >> 4);
    int q = threadIdx.x & 15;
    if (node >= Nn) return;
    int beg = row_ptr[node], end = row_ptr[node + 1];
    float a[8] = {};
    int j = beg;
    for (; j + 1 < end; j += 2) {
        int s0 = csr[j], s1 = csr[j + 1];
        uint4 r0 = *(const uint4*)(xb + (size_t)s0 * F_DIM + q * 8);
        uint4 r1 = *(const uint4*)(xb + (size_t)s1 * F_DIM + q * 8);
        a[0] += bf2f(r0.x & 0xffff) + bf2f(r1.x & 0xffff);
        a[1] += bf2f(r0.x >> 16)    + bf2f(r1.x >> 16);
        a[2] += bf2f(r0.y & 0xffff) + bf2f(r1.y & 0xffff);
        a[3] += bf2f(r0.y >> 16)    + bf2f(r1.y >> 16);
        a[4] += bf2f(r0.z & 0xffff) + bf2f(r1.z & 0xffff);
        a[5] += bf2f(r0.z >> 16)    + bf2f(r1.z >> 16);
        a[6] += bf2f(r0.w & 0xffff) + bf2f(r1.w & 0xffff);
        a[7] += bf2f(r0.w >> 16)    + bf2f(r1.w >> 16);
    }
    if (j < end) {
        int s0 = csr[j];
        uint4 r0 = *(const uint4*)(xb + (size_t)s0 * F_DIM + q * 8);
        a[0] += bf2f(r0.x & 0xffff);
        a[1] += bf2f(r0.x >> 16);
        a[2] += bf2f(r0.y & 0xffff);
        a[3] += bf2f(r0.y >> 16);
        a[4] += bf2f(r0.z & 0xffff);
        a[5] += bf2f(r0.z >> 16);
        a[6] += bf2f(r0.w & 0xffff);
        a[7] += bf2f(r0.w >> 16);
    }
    float inv = 1.0f / fmaxf((float)(end - beg), 1.0f);
    uint4 o;
    o.x = (unsigned)f2bf(a[0] * inv) | ((unsigned)f2bf(a[1] * inv) << 16);
    o.y = (unsigned)f2bf(a[2] * inv) | ((unsigned)f2bf(a[3] * inv) << 16);
    o.z = (unsigned)f2bf(a[4] * inv) | ((unsigned)f2bf(a[5] * inv) << 16);
    o.w = (unsigned)f2bf(a[6] * inv) | ((unsigned)f2bf(a[7] * inv) << 16);
    *(uint4*)(aggb + (size_t)node * F_DIM + q * 8) = o;
}

// 128x128 tile, K=256 in 4 steps of 64. 4 waves (2x2), each 64x64 output.
__global__ __launch_bounds__(256)
void gemm_mfma(const unsigned short* __restrict__ aggb, const unsigned short* __restrict__ xb,
               const unsigned short* __restrict__ Wb, const float* __restrict__ b1l,
               const float* __restrict__ W2l, const float* __restrict__ W2r,
               float* __restrict__ tv, float* __restrict__ rv, int Nn) {
    __shared__ unsigned short Al[128 * 64];   // 16 KB
    __shared__ unsigned short Bl[128 * 64];   // 16 KB
    int mb = blockIdx.x >> 1;
    int jb = blockIdx.x & 1;
    int m0 = mb * 128;
    int tid = threadIdx.x;
    int lane = tid & 63, wid = tid >> 6;
    int wm = wid >> 1, wj = wid & 1;

    f4 acc[4][4] = {};

    for (int kstep = 0; kstep < 4; ++kstep) {
        const unsigned short* Asrc = (kstep < 2) ? aggb : xb;
        int kbase = (kstep & 1) * 64;
        #pragma unroll
        for (int pass = 0; pass < 4; ++pass) {
            int c = tid + pass * 256;
            int m = c >> 3, kc = c & 7;
            int gn = m0 + m;
            uint4 v = make_uint4(0u, 0u, 0u, 0u);
            if (gn < Nn) v = *(const uint4*)(Asrc + (size_t)gn * F_DIM + kbase + kc * 8);
            int byte = (m * 128 + kc * 16) ^ ((m & 7) << 4);
            *(uint4*)((char*)Al + byte) = v;
        }
        #pragma unroll
        for (int pass = 0; pass < 4; ++pass) {
            int c = tid + pass * 256;
            int jj = c >> 3, kc = c & 7;
            uint4 v = *(const uint4*)(Wb + (size_t)(jb * 128 + jj) * NFEAT2 + kstep * 64 + kc * 8);
            int byte = (jj * 128 + kc * 16) ^ ((jj & 7) << 4);
            *(uint4*)((char*)Bl + byte) = v;
        }
        __syncthreads();

        #pragma unroll
        for (int ks = 0; ks < 2; ++ks) {
            int kk2 = (ks * 32 + ((lane >> 4) << 3)) * 2;   // byte offset in row
            b8 af[4], bfr[4];
            #pragma unroll
            for (int fm = 0; fm < 4; ++fm) {
                int m = (wm << 6) + (fm << 4) + (lane & 15);
                int byte = (m * 128 + kk2) ^ ((m & 7) << 4);
                af[fm] = *(const b8*)((const char*)Al + byte);
            }
            #pragma unroll
            for (int fj = 0; fj < 4; ++fj) {
                int jj = (wj << 6) + (fj << 4) + (lane & 15);
                int byte = (jj * 128 + kk2) ^ ((jj & 7) << 4);
                bfr[fj] = *(const b8*)((const char*)Bl + byte);
            }
            #pragma unroll
            for (int fm = 0; fm < 4; ++fm)
                #pragma unroll
                for (int fj = 0; fj < 4; ++fj)
                    acc[fm][fj] = __builtin_amdgcn_mfma_f32_16x16x32_bf16(
                        af[fm], bfr[fj], acc[fm][fj], 0, 0, 0);
        }
        __syncthreads();
    }

    float bb[4], wl[4], wr[4];
    #pragma unroll
    for (int fj = 0; fj < 4; ++fj) {
        int j_abs = jb * 128 + (wj << 6) + (fj << 4) + (lane & 15);
        bb[fj] = b1l[j_abs];
        wl[fj] = W2l[j_abs];
        wr[fj] = W2r[j_abs];
    }
    #pragma unroll
    for (int fm = 0; fm < 4; ++fm) {
        #pragma unroll
        for (int reg = 0; reg < 4; ++reg) {
            int row = m0 + (wm << 6) + (fm << 4) + ((lane >> 4) << 2) + reg;
            float tp = 0.f, rp = 0.f;
            #pragma unroll
            for (int fj = 0; fj < 4; ++fj) {
                float h = fmaxf(acc[fm][fj][reg] + bb[fj], 0.0f);
                tp += wl[fj] * h;
                rp += wr[fj] * h;
            }
            #pragma unroll
            for (int mask = 1; mask < 16; mask <<= 1) {
                tp += __shfl_xor(tp, mask, 64);
                rp += __shfl_xor(rp, mask, 64);
            }
            if ((lane & 15) == 0 && row < Nn) {
                atomicAdd(&tv[row], tp);
                atomicAdd(&rv[row], rp);
            }
        }
    }
}

__global__ void final_k(const float* __restrict__ t, const int* __restrict__ row_ptr,
                        const int* __restrict__ csr, const float* __restrict__ r,
                        const float* __restrict__ b2l,
                        const float* __restrict__ Wmu, const float* __restrict__ bmu,
                        const float* __restrict__ Wlv, const float* __restrict__ blv,
                        const float* __restrict__ eps, float* __restrict__ out, int Nn) {
    int i = blockIdx.x * blockDim.x + threadIdx.x;
    if (i >= Nn) return;
    int beg = row_ptr[i], end = row_ptr[i + 1];
    float s = 0.f;
    for (int j = beg; j < end; ++j) s += t[csr[j]];
    float z = s / fmaxf((float)(end - beg), 1.0f) + b2l[0] + r[i];
    float mu = z * Wmu[0] + bmu[0];
    float lv = z * Wlv[0] + blv[0];
    out[i] = mu + eps[i] * expf(lv);
}

extern "C" void kernel_launch(void* const* d_in, const int* in_sizes, int n_in,
                              void* d_out, int out_size, void* d_ws, size_t ws_size,
                              hipStream_t stream) {
    const float* x   = (const float*)d_in[0];
    const int*   ei  = (const int*)d_in[1];
    const float* W1l = (const float*)d_in[2];
    const float* b1l = (const float*)d_in[3];
    const float* W1r = (const float*)d_in[4];
    const float* W2l = (const float*)d_in[5];
    const float* b2l = (const float*)d_in[6];
    const float* W2r = (const float*)d_in[7];
    // d_in[8..10] = Wal, bal, War : dead (softmax over size-1 axis == 1)
    const float* Wmu = (const float*)d_in[11];
    const float* bmu = (const float*)d_in[12];
    const float* Wlv = (const float*)d_in[13];
    const float* blv = (const float*)d_in[14];
    const float* eps = (const float*)d_in[15];
    float* out = (float*)d_out;

    const int Nn = in_sizes[0] / F_DIM;   // 100000
    const int E  = in_sizes[1] / 2;       // 1600000
    const int* src = ei;
    const int* dst = ei + E;
    const int nbuk = (Nn + BUK_SZ - 1) >> BUK_BITS;      // 782
    const int chunk = (E + GROUPS - 1) / GROUPS;         // 12500

    char* ws = (char*)d_ws;
    float*          tv      = (float*)(ws + 0);              // N
    float*          rv      = (float*)(ws + 400000);         // N
    int*            row_ptr = (int*)(ws + 800000);           // N+1
    int*            bbase   = (int*)(ws + 1200064);          // nbuk+1
    int*            hist    = (int*)(ws + 1203200);          // GROUPS*nbuk
    int*            gbase   = (int*)(ws + 1603584);          // nbuk*GROUPS (T aliases)
    int*            Tbuf    = gbase;                          // colsum output (consumed before colscan writes)
    int*            csr     = (int*)(ws + 2003968);          // E ints
    unsigned short* xb      = (unsigned short*)(ws + 8403968);   // N*128 bf16
    unsigned short* aggb    = (unsigned short*)(ws + 34003968);  // N*128 bf16
    uint2*          ebuf    = (uint2*)(ws + 34003968);           // E*8B (aliases aggb)
    unsigned short* Wb      = (unsigned short*)(ws + 59603968);  // 256*256 bf16

    hipMemsetAsync(ws, 0, 800000, stream);   // tv, rv

    cvt_x<<<(Nn * F_DIM / 4 + 255) / 256, 256, 0, stream>>>(x, xb, Nn * F_DIM / 4);
    prep_w<<<256, 256, 0, stream>>>(W1l, W1r, Wb);

    hist_k<<<GROUPS, 256, 0, stream>>>(dst, hist, E, nbuk, chunk);
    colsum_k<<<(nbuk + 255) / 256, 256, 0, stream>>>(hist, Tbuf, nbuk);
    exscan_k<<<1, 1024, 0, stream>>>(Tbuf, bbase, nbuk);
    colscan_k<<<nbuk, GROUPS, 0, stream>>>(hist, bbase, gbase, nbuk);
    scatter2_k<<<GROUPS, 256, 0, stream>>>(src, dst, gbase, ebuf, E, nbuk, chunk);
    fill3_k<<<nbuk, 256, 0, stream>>>(ebuf, bbase, row_ptr, csr, Nn, nbuk);

    gather_mean<<<(Nn + 15) / 16, 256, 0, stream>>>(xb, row_ptr, csr, aggb, Nn);

    {
        int mblocks = (Nn + 127) / 128;
        gemm_mfma<<<mblocks * 2, 256, 0, stream>>>(aggb, xb, Wb, b1l, W2l, W2r,
                                                   tv, rv, Nn);
    }

    final_k<<<(Nn + 255) / 256, 256, 0, stream>>>(tv, row_ptr, csr, rv, b2l,
                                                  Wmu, bmu, Wlv, blv, eps, out, Nn);
}